// Round 10
// baseline (82.697 us; speedup 1.0000x reference)
//
#include <hip/hip_runtime.h>

// Closed form of the QLayer circuit (verified r1-r9, absmax 1.95e-3):
//   c_i = cos(x_i + theta_i); z[0]=c1..c7, z[w]=c0..cw (w>=1).
//   G = z z^T / sqrt(8); attn = softmax rows (no max-pass, |s|<=2.83);
//   o = attn @ z; y = o @ W^T + b (MFMA 16x16x32 bf16, m89 fragment maps).
//
// R10 = R9 body + REPS=48 DIAGNOSTIC REPEAT (same-round overhead split).
//   Motivation: every launch-geometry and body change lands at 9.8-11.0us
//   one-shot; warm marginal (R8) is 1.55us/rep; and we have had NO rocprof
//   rows for our kernel since R1 (39us poison fills own the top-5). The
//   split dur_us = harness_overhead + kernel_gpu is unconstrained by any
//   same-run data. This dispatch runs ~75-90us -> enters top-5 -> gives
//   (a) overhead = dur_us - rocprof_dur directly, (b) steady-state
//   VALUBusy/Occupancy/LDS-conflict/FETCH for the real body.
//   Pre-committed decision: overhead <=3us -> attack cold path next;
//   >=5us -> harness floor, restore best one-shot kernel and declare.
//   Reps use an asm-opaque zero offset (rule #17) -> idempotent, exact
//   same output bits as R9.

#define BLK_TOK 64
#define REPS 48

typedef __attribute__((ext_vector_type(8))) short short8;
typedef __attribute__((ext_vector_type(4))) float f32x4;

__device__ inline unsigned short f2bf(float f) {
    unsigned u = __float_as_uint(f);
    u += 0x7FFF + ((u >> 16) & 1);          // RNE
    return (unsigned short)(u >> 16);
}

__device__ inline short8 pack_bf16x8(float4 a, float4 b) {
    short8 r;
    r[0] = (short)f2bf(a.x); r[1] = (short)f2bf(a.y);
    r[2] = (short)f2bf(a.z); r[3] = (short)f2bf(a.w);
    r[4] = (short)f2bf(b.x); r[5] = (short)f2bf(b.y);
    r[6] = (short)f2bf(b.z); r[7] = (short)f2bf(b.w);
    return r;
}

__global__ __launch_bounds__(1024)
void mhaq_fused10(const float* __restrict__ x,
                  const float* __restrict__ theta,
                  const float* __restrict__ W,
                  const float* __restrict__ bias,
                  float* __restrict__ out,
                  int n_tokens)
{
    __shared__ __align__(16) float          zs[BLK_TOK * 68]; // f32, pad 4
    __shared__ __align__(16) unsigned short os[BLK_TOK * 72]; // bf16, pad 8

    const int tid = threadIdx.x;
    const int tl  = tid >> 4;           // token within block, 0..63
    const int s   = tid & 15;
    const int h   = s >> 1;             // head this thread attends
    const int q   = s & 1;              // wire/t/d half
    const int blockbase = blockIdx.x * BLK_TOK;
    const int token = blockbase + tl;

    // phase-3 wave mapping: 16 waves = 4 token-tiles x 4 j-quarters
    const int wave = tid >> 6;          // 0..15
    const int lane = tid & 63;
    const int lr   = lane & 15;
    const int lg   = lane >> 4;         // 0..3
    const int tile = wave >> 2;         // 0..3 -> tokens tile*16..+16
    const int jq   = wave & 3;
    const int j    = jq * 16 + lr;

    // ---- theta (uniform) + per-thread wire selection ----
    const float tw0 = theta[0], tw1 = theta[1], tw2 = theta[2], tw3 = theta[3];
    const float tw4 = theta[4], tw5 = theta[5], tw6 = theta[6], tw7 = theta[7];
    const float tq0 = q ? tw4 : tw0;
    const float tq1 = q ? tw5 : tw1;
    const float tq2 = q ? tw6 : tw2;
    const float tq3 = q ? tw7 : tw3;

    // ---- W + bias once per block; pack to bf16 once ----
    const float bj = bias[j];
    short8 bfrag0, bfrag1;
    {
        const float4* __restrict__ Wv = reinterpret_cast<const float4*>(W);
        const int base = j * 16 + lg * 2;       // (j*64 + kt*32 + lg*8)/4
        float4 w00 = Wv[base],     w01 = Wv[base + 1];
        float4 w10 = Wv[base + 8], w11 = Wv[base + 9];
        bfrag0 = pack_bf16x8(w00, w01);
        bfrag1 = pack_bf16x8(w10, w11);
    }

    size_t xoff = 0;                    // always 0; asm-opaque per rep

    #pragma unroll 1
    for (int rep = 0; rep < REPS; ++rep) {
        asm volatile("" : "+s"(xoff)); // defeat cross-rep CSE/DSE
        const float* __restrict__ xr   = x + xoff;
        float*       __restrict__ outr = out + xoff;

        // ---- x load: thread s owns features s*4..s*4+3 of its token ----
        float4 xv = make_float4(0.f, 0.f, 0.f, 0.f);
        if (token < n_tokens)
            xv = *reinterpret_cast<const float4*>(
                xr + (size_t)token * 64 + s * 4);

        // ---- phase 1: 4 cos; partner half via shfl_xor(1) (DPP) ----
        float cq0 = __cosf(xv.x + tq0);
        float cq1 = __cosf(xv.y + tq1);
        float cq2 = __cosf(xv.z + tq2);
        float cq3 = __cosf(xv.w + tq3);
        float cp0 = __shfl_xor(cq0, 1, 64);
        float cp1 = __shfl_xor(cq1, 1, 64);
        float cp2 = __shfl_xor(cq2, 1, 64);
        float cp3 = __shfl_xor(cq3, 1, 64);
        float l0 = q ? cp0 : cq0;       // wires 0-3
        float l1 = q ? cp1 : cq1;
        float l2 = q ? cp2 : cq2;
        float l3 = q ? cp3 : cq3;
        float h0 = q ? cq0 : cp0;       // wires 4-7
        float h1 = q ? cq1 : cp1;
        float h2 = q ? cq2 : cp2;
        float h3 = q ? cq3 : cp3;
        float p1 = l0 * l1;
        float p2 = p1 * l2;
        float p3 = p2 * l3;
        float p4 = p3 * h0;
        float p5 = p4 * h1;
        float p6 = p5 * h2;
        float p7 = p6 * h3;
        float t12  = l1 * l2;
        float t123 = t12 * l3;
        float hh   = h0 * h1;
        float hh2  = hh * h2;
        float hh3  = hh2 * h3;
        float s1   = t123 * hh3;        // c1*...*c7
        float4 zst = q ? make_float4(p4, p5, p6, p7)
                       : make_float4(s1, p1, p2, p3);
        *reinterpret_cast<float4*>(zs + tl * 68 + s * 4) = zst;
        __syncthreads();

        // ---- phase 2: head h, own t-half + partner t-half ----
        {
            const float* zrow = zs + tl * 68;
            const float zh[8] = {s1, p1, p2, p3, p4, p5, p6, p7};

            float zt8[32];              // rows t = q*4 .. q*4+3 (all 8 cols)
            #pragma unroll
            for (int i = 0; i < 8; ++i)
                *reinterpret_cast<float4*>(&zt8[i * 4]) =
                    *reinterpret_cast<const float4*>(&zrow[q * 32 + i * 4]);

            float zo[16];               // rows (1-q)*4+tt, cols q*4..q*4+3
            #pragma unroll
            for (int tt = 0; tt < 4; ++tt)
                *reinterpret_cast<float4*>(&zo[tt * 4]) =
                    *reinterpret_cast<const float4*>(
                        &zrow[((1 - q) * 4 + tt) * 8 + q * 4]);

            const float scale = 0.35355339059327373f;  // 1/sqrt(8)
            float e[4];
            float psum = 0.f;
            #pragma unroll
            for (int tt = 0; tt < 4; ++tt) {
                float sd = 0.f;
                #pragma unroll
                for (int d = 0; d < 8; ++d)
                    sd = fmaf(zh[d], zt8[tt * 8 + d], sd);
                e[tt] = __expf(sd * scale);
                psum += e[tt];
            }
            float tot = psum + __shfl_xor(psum, 1, 64);
            float inv = 1.0f / tot;

            float ep[4];
            #pragma unroll
            for (int tt = 0; tt < 4; ++tt)
                ep[tt] = __shfl_xor(e[tt], 1, 64);

            unsigned short oh[4];
            #pragma unroll
            for (int dd = 0; dd < 4; ++dd) {
                float acc = 0.f;
                #pragma unroll
                for (int tt = 0; tt < 4; ++tt) {
                    float zown = q ? zt8[tt * 8 + 4 + dd] : zt8[tt * 8 + dd];
                    acc = fmaf(e[tt],  zown,            acc);
                    acc = fmaf(ep[tt], zo[tt * 4 + dd], acc);
                }
                oh[dd] = f2bf(acc * inv);
            }
            *reinterpret_cast<ushort4*>(&os[tl * 72 + h * 8 + q * 4]) =
                make_ushort4(oh[0], oh[1], oh[2], oh[3]);
        }
        __syncthreads();

        // ---- phase 3: y = o @ W^T + b via MFMA; wave (tile, jq) ----
        {
            const unsigned short* orow = &os[(tile * 16 + lr) * 72];
            short8 afrag0 = *reinterpret_cast<const short8*>(&orow[lg * 8]);
            short8 afrag1 = *reinterpret_cast<const short8*>(&orow[32 + lg * 8]);
            f32x4 acc = {bj, bj, bj, bj};
            acc = __builtin_amdgcn_mfma_f32_16x16x32_bf16(afrag0, bfrag0, acc, 0, 0, 0);
            acc = __builtin_amdgcn_mfma_f32_16x16x32_bf16(afrag1, bfrag1, acc, 0, 0, 0);
            #pragma unroll
            for (int r = 0; r < 4; ++r) {
                int trow = blockbase + tile * 16 + lg * 4 + r;
                if (trow < n_tokens)
                    outr[(size_t)trow * 64 + j] = acc[r];
            }
        }
    }
}

extern "C" void kernel_launch(void* const* d_in, const int* in_sizes, int n_in,
                              void* d_out, int out_size, void* d_ws, size_t ws_size,
                              hipStream_t stream)
{
    const float* x     = (const float*)d_in[0];
    const float* theta = (const float*)d_in[1];
    const float* W     = (const float*)d_in[2];
    const float* b     = (const float*)d_in[3];
    float* out         = (float*)d_out;

    const int n_tokens = in_sizes[0] / 64;                        // 16384
    const int blocks   = (n_tokens + BLK_TOK - 1) / BLK_TOK;      // 256
    mhaq_fused10<<<blocks, 1024, 0, stream>>>(x, theta, W, b, out, n_tokens);
}

// Round 11
// 9.797 us; speedup vs baseline: 8.4414x; 8.4414x over previous
//
#include <hip/hip_runtime.h>

// Closed form of the QLayer circuit (verified r1-r10, absmax 1.95e-3):
//   c_i = cos(x_i + theta_i); z[0]=c1..c7, z[w]=c0..cw (w>=1).
//   G = z z^T / sqrt(8); attn = softmax rows (no max-pass, |s|<=2.83);
//   o = attn @ z; y = o @ W^T + b (MFMA 16x16x32 bf16, m89 fragment maps).
//
// R11 = restore best one-shot (R5 geometry, R8 body) + last cold-path opts.
//   R10 diagnostics: dur_us = 8.17us fixed + 1.553us/rep; warm body is
//   VALU-issue-bound (VALUBusy 67%), conflicts ~3%, FETCH cache-resident.
//   Body ~1.55us is ~1.2x the 1.3us memory floor -> body is done; the
//   fixed 8.2us is launch/drain overhead (invariant to WG count, block
//   size, body size across R3-R9). Kernel-side residue attacked here:
//   (a) barrier 1 -> intra-wave lgkmcnt(0)+sched_barrier (16 thr/token,
//       256-thr block: token's producers+consumers share one wave);
//   (b) W bf16 pack moved AFTER barrier 2 (R8/R9 packed before phase 1,
//       draining W vmcnt into the cold phase-1 critical path).
//   Pre-committed: neutral (9.3-9.9) -> declare structural floor next round.
// Fragment maps (m89-verified): A: lane l -> A[m=l&15][k=(l>>4)*8+i]
//   B: lane l -> B[k=(l>>4)*8+i][n=l&15]; C: reg r -> [m=(l>>4)*4+r][n=l&15]

#define TOK_PER_BLK 16

typedef __attribute__((ext_vector_type(8))) short short8;
typedef __attribute__((ext_vector_type(4))) float f32x4;

__device__ inline unsigned short f2bf(float f) {
    unsigned u = __float_as_uint(f);
    u += 0x7FFF + ((u >> 16) & 1);          // RNE
    return (unsigned short)(u >> 16);
}

__device__ inline short8 pack_bf16x8(float4 a, float4 b) {
    short8 r;
    r[0] = (short)f2bf(a.x); r[1] = (short)f2bf(a.y);
    r[2] = (short)f2bf(a.z); r[3] = (short)f2bf(a.w);
    r[4] = (short)f2bf(b.x); r[5] = (short)f2bf(b.y);
    r[6] = (short)f2bf(b.z); r[7] = (short)f2bf(b.w);
    return r;
}

__global__ __launch_bounds__(256, 4)
void mhaq_fused11(const float* __restrict__ x,
                  const float* __restrict__ theta,
                  const float* __restrict__ W,
                  const float* __restrict__ bias,
                  float* __restrict__ out,
                  int n_tokens)
{
    __shared__ __align__(16) float          zs[TOK_PER_BLK * 68]; // f32, pad 4
    __shared__ __align__(16) unsigned short os[TOK_PER_BLK * 72]; // bf16, pad 8

    const int tid = threadIdx.x;
    const int tl  = tid >> 4;           // token within block, 0..15
    const int s   = tid & 15;
    const int h   = s >> 1;             // head this thread attends
    const int q   = s & 1;              // wire/t/d half
    const int blockbase = blockIdx.x * TOK_PER_BLK;
    const int token = blockbase + tl;

    const int lane = tid & 63;
    const int wave = tid >> 6;          // 0..3 -> j-quarter
    const int lr   = lane & 15;
    const int lg   = lane >> 4;         // 0..3
    const int j    = wave * 16 + lr;

    // ---- x load FIRST (phase-1 critical path; W stays behind it in vmcnt) ----
    float4 xv = make_float4(0.f, 0.f, 0.f, 0.f);
    if (token < n_tokens)
        xv = *reinterpret_cast<const float4*>(x + (size_t)token * 64 + s * 4);

    // ---- theta (uniform scalar loads) + per-thread wire selection ----
    const float tw0 = theta[0], tw1 = theta[1], tw2 = theta[2], tw3 = theta[3];
    const float tw4 = theta[4], tw5 = theta[5], tw6 = theta[6], tw7 = theta[7];
    const float tq0 = q ? tw4 : tw0;
    const float tq1 = q ? tw5 : tw1;
    const float tq2 = q ? tw6 : tw2;
    const float tq3 = q ? tw7 : tw3;

    // ---- W + bias loads issued now, CONSUMED only after barrier 2 ----
    float4 wf00, wf01, wf10, wf11;
    float  bj;
    {
        const float4* __restrict__ Wv = reinterpret_cast<const float4*>(W);
        const int base = j * 16 + lg * 2;       // (j*64 + kt*32 + lg*8)/4
        wf00 = Wv[base];     wf01 = Wv[base + 1];
        wf10 = Wv[base + 8]; wf11 = Wv[base + 9];
        bj = bias[j];
    }

    // ---- phase 1: 4 cos; partner half via shfl_xor(1) (DPP) ----
    float cq0 = __cosf(xv.x + tq0);
    float cq1 = __cosf(xv.y + tq1);
    float cq2 = __cosf(xv.z + tq2);
    float cq3 = __cosf(xv.w + tq3);
    float cp0 = __shfl_xor(cq0, 1, 64);
    float cp1 = __shfl_xor(cq1, 1, 64);
    float cp2 = __shfl_xor(cq2, 1, 64);
    float cp3 = __shfl_xor(cq3, 1, 64);
    float l0 = q ? cp0 : cq0;           // wires 0-3
    float l1 = q ? cp1 : cq1;
    float l2 = q ? cp2 : cq2;
    float l3 = q ? cp3 : cq3;
    float h0 = q ? cq0 : cp0;           // wires 4-7
    float h1 = q ? cq1 : cp1;
    float h2 = q ? cq2 : cp2;
    float h3 = q ? cq3 : cp3;
    float p1 = l0 * l1;
    float p2 = p1 * l2;
    float p3 = p2 * l3;
    float p4 = p3 * h0;
    float p5 = p4 * h1;
    float p6 = p5 * h2;
    float p7 = p6 * h3;
    float t12  = l1 * l2;
    float t123 = t12 * l3;
    float hh   = h0 * h1;
    float hh2  = hh * h2;
    float hh3  = hh2 * h3;
    float s1   = t123 * hh3;            // c1*...*c7
    float4 zst = q ? make_float4(p4, p5, p6, p7)
                   : make_float4(s1, p1, p2, p3);
    *reinterpret_cast<float4*>(zs + tl * 68 + s * 4) = zst;

    // z-exchange is intra-wave (token's 16 producers/consumers in one wave):
    // wave-level LDS drain replaces __syncthreads (rule #18: pin scheduler).
    asm volatile("s_waitcnt lgkmcnt(0)" ::: "memory");
    __builtin_amdgcn_sched_barrier(0);

    // ---- phase 2: head h, own t-half + partner t-half; o -> bf16 LDS ----
    {
        const float* zrow = zs + tl * 68;
        const float zh[8] = {s1, p1, p2, p3, p4, p5, p6, p7}; // own head, regs

        float zt8[32];                  // rows t = q*4 .. q*4+3 (all 8 cols)
        #pragma unroll
        for (int i = 0; i < 8; ++i)
            *reinterpret_cast<float4*>(&zt8[i * 4]) =
                *reinterpret_cast<const float4*>(&zrow[q * 32 + i * 4]);

        float zo[16];                   // rows (1-q)*4+tt, cols q*4..q*4+3
        #pragma unroll
        for (int tt = 0; tt < 4; ++tt)
            *reinterpret_cast<float4*>(&zo[tt * 4]) =
                *reinterpret_cast<const float4*>(
                    &zrow[((1 - q) * 4 + tt) * 8 + q * 4]);

        const float scale = 0.35355339059327373f;  // 1/sqrt(8)
        float e[4];
        float psum = 0.f;
        #pragma unroll
        for (int tt = 0; tt < 4; ++tt) {
            float sd = 0.f;
            #pragma unroll
            for (int d = 0; d < 8; ++d)
                sd = fmaf(zh[d], zt8[tt * 8 + d], sd);
            e[tt] = __expf(sd * scale);
            psum += e[tt];
        }
        float tot = psum + __shfl_xor(psum, 1, 64);
        float inv = 1.0f / tot;

        float ep[4];
        #pragma unroll
        for (int tt = 0; tt < 4; ++tt)
            ep[tt] = __shfl_xor(e[tt], 1, 64);

        // o_dd = sum_own e[tt]*z[q*4+tt][q*4+dd] + sum_part ep[tt]*zo[tt][dd]
        unsigned short oh[4];
        #pragma unroll
        for (int dd = 0; dd < 4; ++dd) {
            float acc = 0.f;
            #pragma unroll
            for (int tt = 0; tt < 4; ++tt) {
                float zown = q ? zt8[tt * 8 + 4 + dd] : zt8[tt * 8 + dd];
                acc = fmaf(e[tt],  zown,            acc);
                acc = fmaf(ep[tt], zo[tt * 4 + dd], acc);
            }
            oh[dd] = f2bf(acc * inv);
        }
        *reinterpret_cast<ushort4*>(&os[tl * 72 + h * 8 + q * 4]) =
            make_ushort4(oh[0], oh[1], oh[2], oh[3]);
    }
    __syncthreads();                    // os IS cross-wave -> keep

    // ---- phase 3: y = o @ W^T + b via MFMA; W packed HERE (post-barrier) ----
    {
        short8 bfrag0 = pack_bf16x8(wf00, wf01);
        short8 bfrag1 = pack_bf16x8(wf10, wf11);
        const unsigned short* orow = &os[lr * 72];
        short8 afrag0 = *reinterpret_cast<const short8*>(&orow[lg * 8]);
        short8 afrag1 = *reinterpret_cast<const short8*>(&orow[32 + lg * 8]);
        f32x4 acc = {bj, bj, bj, bj};
        acc = __builtin_amdgcn_mfma_f32_16x16x32_bf16(afrag0, bfrag0, acc, 0, 0, 0);
        acc = __builtin_amdgcn_mfma_f32_16x16x32_bf16(afrag1, bfrag1, acc, 0, 0, 0);
        #pragma unroll
        for (int r = 0; r < 4; ++r) {
            int trow = blockbase + lg * 4 + r;
            if (trow < n_tokens)
                out[(size_t)trow * 64 + j] = acc[r];
        }
    }
}

extern "C" void kernel_launch(void* const* d_in, const int* in_sizes, int n_in,
                              void* d_out, int out_size, void* d_ws, size_t ws_size,
                              hipStream_t stream)
{
    const float* x     = (const float*)d_in[0];
    const float* theta = (const float*)d_in[1];
    const float* W     = (const float*)d_in[2];
    const float* b     = (const float*)d_in[3];
    float* out         = (float*)d_out;

    const int n_tokens = in_sizes[0] / 64;                            // 16384
    const int blocks   = (n_tokens + TOK_PER_BLK - 1) / TOK_PER_BLK;  // 1024
    mhaq_fused11<<<blocks, 256, 0, stream>>>(x, theta, W, b, out, n_tokens);
}